// Round 5
// baseline (667.546 us; speedup 1.0000x reference)
//
#include <hip/hip_runtime.h>
#include <hip/hip_bf16.h>
#include <stdint.h>

#define DIM 512
#define HIDDEN 2048
#define BATCH 16384

using bf16 = __hip_bfloat16;
typedef float f32x4 __attribute__((ext_vector_type(4)));
typedef short bf16x8 __attribute__((ext_vector_type(8)));

__device__ __forceinline__ float bf2f(bf16 x) { return __bfloat162float(x); }
__device__ __forceinline__ bf16 f2bf(float x) { return __float2bfloat16(x); }

// fast tanh: 1 - 2/(e^{2x}+1).
__device__ __forceinline__ float fast_tanh(float x) {
    float e = __expf(2.0f * x);
    return 1.0f - 2.0f * __builtin_amdgcn_rcpf(e + 1.0f);
}

__device__ __forceinline__ f32x4 mfma16(bf16x8 a, bf16x8 b, f32x4 c) {
    return __builtin_amdgcn_mfma_f32_16x16x32_bf16(a, b, c, 0, 0, 0);
}

__device__ __forceinline__ void BARP() {
    __builtin_amdgcn_sched_barrier(0);
    __builtin_amdgcn_s_barrier();
    __builtin_amdgcn_sched_barrier(0);
}
// counted lgkmcnt + sched fence (rule #18: MFMA must not hoist above the wait)
#define LGKM(N) do { asm volatile("s_waitcnt lgkmcnt(" #N ")" ::: "memory"); \
                     __builtin_amdgcn_sched_barrier(0); } while (0)
#define VMCNT(N) asm volatile("s_waitcnt vmcnt(" #N ")" ::: "memory")

// stage one K-half of a 256-row tile: 256 rows x 32 cols bf16 = 16KB.
// LDS linear [row][slot(16B)] (4 slots/row). Swizzle f(row) = (row>>1)&3
// applied on the GLOBAL source (rule #21); ds_read side XORs the same f.
// 64B rows -> bank quad = parity only; f=(row>>1)&3 spreads each 16-lane
// read group over all 8 quads 2x (2-way = free, m136). Verified: 0 conflicts.
__device__ __forceinline__ void stage_half(const bf16* __restrict__ G, int grow0,
                                           int Kdim, int kbase, bf16* lds,
                                           int elem_base, int wave, int srow4, int gs8)
{
#pragma unroll
    for (int i = 0; i < 2; ++i) {
        const int q = wave * 2 + i;
        const bf16* ga = G + (size_t)(grow0 + q * 16 + srow4) * Kdim + kbase + gs8;
        __builtin_amdgcn_global_load_lds(
            (const __attribute__((address_space(1))) void*)ga,
            (__attribute__((address_space(3))) void*)(lds + elem_base + q * 512), 16, 0, 0);
    }
}

// ---------------------------------------------------------------------------
// Pipelined 256x256 GEMM: C = A[M,K] @ Bt[N,K]^T (bf16 row-major).
// 8 waves (2M x 4N), per-wave 128x64, BK=64, LDS 128KB dbuf.
// Register-pipelined schedule, ONE barrier + ONE full drain per K-tile:
//   s0: issue A47(k0) reads   ; lgkm(4) ; MFMA acc[0..3] (A03,B0)
//   s1: issue A03(k1)+B1 reads; lgkm(8) ; MFMA acc[4..7] (A47,B0)
//   s2: issue A47(k1) reads   ; lgkm(4) ; MFMA acc[0..3] (A03,B1)
//   s3: lgkm(0); vmcnt(0); BARRIER;
//       stage tile t+2 into freed buf; issue next-tile A03(k0)+B0 reads;
//       MFMA acc[4..7] (A47,B1)
// Each sub-phase's reads are issued one MFMA burst (~620 cyc) before their
// counted wait -> LDS drain hides under MFMA (AITER pattern, counted never-0
// mid-tile). vmcnt(0) at the boundary has a full-tile issue-to-wait distance.
// ---------------------------------------------------------------------------
template <int MODE>
__global__ __launch_bounds__(512, 2)
void gemm8(const bf16* __restrict__ A, const bf16* __restrict__ Bt,
           int M, int N, int K,
           const float* __restrict__ bias,
           bf16* __restrict__ out1, bf16* __restrict__ out2,
           const float* __restrict__ u3, const bf16* __restrict__ h1s)
{
    __shared__ bf16 lds[65536];   // 128 KiB
    const int tid  = threadIdx.x;
    const int lane = tid & 63;
    const int wave = tid >> 6;

    // XCD-aware, M-major within each XCD chunk (A-panel L2 locality)
    const int nwg = gridDim.x * gridDim.y;
    const int bid = blockIdx.y * gridDim.x + blockIdx.x;
    const int cpx = nwg >> 3;
    const int sw  = (bid & 7) * cpx + (bid >> 3);
    const int nbn = N >> 8;
    const int bm  = sw / nbn;
    const int bn  = sw % nbn;
    const int row0 = bm << 8;
    const int col0 = bn << 8;

    const int wr = wave >> 2;       // 0..1 (M)
    const int wc = wave & 3;        // 0..3 (N)
    const int l15 = lane & 15;

    // ds_read per-lane offsets: row stride 64B, stored slot = (lane>>4) ^ f(row)
    const int slotl    = (((lane >> 4) ^ ((l15 >> 1) & 3)) << 4);
    const int laneoffA = (wr * 128 + l15) * 64 + slotl;
    const int laneoffB = (wc * 64  + l15) * 64 + slotl;
    // staging constants
    const int srow4 = lane >> 2;
    const int gs8   = (((lane & 3) ^ ((lane >> 3) & 3)) << 3);

    const char* ldsc = (const char*)lds;
    f32x4 acc[8][4] = {};
    bf16x8 A03[4], A47[4], B0[4], B1[4];

    const int KT = K >> 6;

    // prologue: stage tile0 -> buf0, tile1 -> buf1
    stage_half(A,  row0, K, 0,  lds, 0,     wave, srow4, gs8);
    stage_half(Bt, col0, K, 0,  lds, 16384, wave, srow4, gs8);
    stage_half(A,  row0, K, 32, lds, 8192,  wave, srow4, gs8);
    stage_half(Bt, col0, K, 32, lds, 24576, wave, srow4, gs8);
    stage_half(A,  row0, K, 64, lds, 32768 + 0,     wave, srow4, gs8);
    stage_half(Bt, col0, K, 64, lds, 32768 + 16384, wave, srow4, gs8);
    stage_half(A,  row0, K, 96, lds, 32768 + 8192,  wave, srow4, gs8);
    stage_half(Bt, col0, K, 96, lds, 32768 + 24576, wave, srow4, gs8);
    VMCNT(8);          // tile0's 8 stage-loads landed (tile1's 8 in flight)
    BARP();
    // first frags of tile0 (8 reads outstanding entering the loop)
#pragma unroll
    for (int j = 0; j < 4; ++j)
        A03[j] = *(const bf16x8*)(ldsc + j * 1024 + laneoffA);
#pragma unroll
    for (int j = 0; j < 4; ++j)
        B0[j]  = *(const bf16x8*)(ldsc + 32768 + j * 1024 + laneoffB);

    for (int t = 0; t < KT; ++t) {
        const int cb = (t & 1) << 16;     // byte base of current buffer

        // ---- s0: MFMA (A03 k0, B0); prefetch A47 k0 ----
#pragma unroll
        for (int j = 0; j < 4; ++j)
            A47[j] = *(const bf16x8*)(ldsc + cb + (4 + j) * 1024 + laneoffA);
        LGKM(4);
        __builtin_amdgcn_s_setprio(1);
#pragma unroll
        for (int m = 0; m < 4; ++m)
#pragma unroll
            for (int n = 0; n < 4; ++n)
                acc[m][n] = mfma16(A03[m], B0[n], acc[m][n]);
        __builtin_amdgcn_s_setprio(0);

        // ---- s1: MFMA (A47 k0, B0); prefetch A03 k1 + B1 ----
#pragma unroll
        for (int j = 0; j < 4; ++j)
            A03[j] = *(const bf16x8*)(ldsc + cb + 16384 + j * 1024 + laneoffA);
#pragma unroll
        for (int j = 0; j < 4; ++j)
            B1[j]  = *(const bf16x8*)(ldsc + cb + 49152 + j * 1024 + laneoffB);
        LGKM(8);
        __builtin_amdgcn_s_setprio(1);
#pragma unroll
        for (int m = 0; m < 4; ++m)
#pragma unroll
            for (int n = 0; n < 4; ++n)
                acc[4 + m][n] = mfma16(A47[m], B0[n], acc[4 + m][n]);
        __builtin_amdgcn_s_setprio(0);

        // ---- s2: MFMA (A03 k1, B1); prefetch A47 k1 ----
#pragma unroll
        for (int j = 0; j < 4; ++j)
            A47[j] = *(const bf16x8*)(ldsc + cb + 16384 + (4 + j) * 1024 + laneoffA);
        LGKM(4);
        __builtin_amdgcn_s_setprio(1);
#pragma unroll
        for (int m = 0; m < 4; ++m)
#pragma unroll
            for (int n = 0; n < 4; ++n)
                acc[m][n] = mfma16(A03[m], B1[n], acc[m][n]);
        __builtin_amdgcn_s_setprio(0);

        // ---- s3: tile boundary ----
        LGKM(0);           // all own reads from cur drained
        VMCNT(0);          // own stage-loads for tile t+1 landed (issued 1 tile ago)
        BARP();            // all waves: cur reads done + next buffer fully staged

        // refill freed buffer with tile t+2
        if (t + 2 < KT) {
            const int k2  = (t + 2) << 6;
            const int ceb = (t & 1) << 15;   // elem base of cur buffer
            stage_half(A,  row0, K, k2,      lds, ceb + 0,     wave, srow4, gs8);
            stage_half(Bt, col0, K, k2,      lds, ceb + 16384, wave, srow4, gs8);
            stage_half(A,  row0, K, k2 + 32, lds, ceb + 8192,  wave, srow4, gs8);
            stage_half(Bt, col0, K, k2 + 32, lds, ceb + 24576, wave, srow4, gs8);
        }
        // first frags of tile t+1 (next buffer)
        const int nb = ((t + 1) & 1) << 16;
#pragma unroll
        for (int j = 0; j < 4; ++j)
            A03[j] = *(const bf16x8*)(ldsc + nb + j * 1024 + laneoffA);
#pragma unroll
        for (int j = 0; j < 4; ++j)
            B0[j]  = *(const bf16x8*)(ldsc + nb + 32768 + j * 1024 + laneoffB);
        // MFMA (A47 k1, B1) under the stage/read issues
        __builtin_amdgcn_s_setprio(1);
#pragma unroll
        for (int m = 0; m < 4; ++m)
#pragma unroll
            for (int n = 0; n < 4; ++n)
                acc[4 + m][n] = mfma16(A47[m], B1[n], acc[4 + m][n]);
        __builtin_amdgcn_s_setprio(0);
    }

    // Epilogue. C/D: col = lane&15, row = (lane>>4)*4 + reg.
    const int c4 = (lane >> 4) << 2;
#pragma unroll
    for (int m = 0; m < 8; ++m) {
        const int growb = row0 + wr * 128 + m * 16 + c4;
#pragma unroll
        for (int n = 0; n < 4; ++n) {
            const int gcol = col0 + wc * 64 + n * 16 + l15;
            const float bz = (MODE == 3) ? 0.0f : bias[gcol];
            const float uu = (MODE == 1) ? u3[gcol] : 0.0f;
#pragma unroll
            for (int r = 0; r < 4; ++r) {
                const size_t idx = (size_t)(growb + r) * N + gcol;
                const float cv = acc[m][n][r];
                if (MODE == 0) {
                    out1[idx] = f2bf(fast_tanh(cv + bz));
                } else if (MODE == 1) {
                    float v = fast_tanh(cv + bz);
                    out1[idx] = f2bf(v);
                    out2[idx] = f2bf(uu * (1.0f - v * v));
                } else { // MODE 3
                    float h = bf2f(h1s[idx]);
                    out1[idx] = f2bf(cv * (1.0f - h * h));
                }
            }
        }
    }
}

// ---------------------------------------------------------------------------
// 128x128 m97-structure GEMM for the N=512 outputs.
// MODE 2: outF[row*513 + col] = acc + bias[col]            (dz_dt)
// MODE 4: trace fused — atomicAdd(out[row*513+512], dot(esum_row, g_row)/3)
// ---------------------------------------------------------------------------
template <int MODE>
__global__ __launch_bounds__(256)
void gemm_bt(const bf16* __restrict__ A, const bf16* __restrict__ Bt,
             int M, int N, int K,
             const float* __restrict__ bias,
             float* __restrict__ outF,
             const float* __restrict__ esum)
{
    __shared__ __align__(128) bf16 As[128 * 64];
    __shared__ __align__(128) bf16 Bs[128 * 64];

    const int tid  = threadIdx.x;
    const int lane = tid & 63;
    const int wave = tid >> 6;

    const int nwg = gridDim.x * gridDim.y;
    const int bid = blockIdx.y * gridDim.x + blockIdx.x;
    const int cpx = nwg >> 3;
    const int sw  = (bid & 7) * cpx + (bid >> 3);
    const int nbn = N >> 7;
    const int bm  = sw / nbn;
    const int bn  = sw % nbn;
    const int row0 = bm << 7;
    const int col0 = bn << 7;

    const int wr = wave >> 1;
    const int wc = wave & 1;

    f32x4 acc[4][4] = {};

    const int srow  = lane >> 3;
    const int sslot = lane & 7;

    const int KT = K >> 6;
    for (int kt = 0; kt < KT; ++kt) {
        const int k0 = kt << 6;
        __syncthreads();
#pragma unroll
        for (int i = 0; i < 4; ++i) {
            const int q   = wave * 4 + i;
            const int row = q * 8 + srow;
            const int gs  = sslot ^ (row & 7);
            const bf16* ga = A  + (size_t)(row0 + row) * K + (k0 + gs * 8);
            const bf16* gb = Bt + (size_t)(col0 + row) * K + (k0 + gs * 8);
            __builtin_amdgcn_global_load_lds(
                (const __attribute__((address_space(1))) void*)ga,
                (__attribute__((address_space(3))) void*)(As + q * 512), 16, 0, 0);
            __builtin_amdgcn_global_load_lds(
                (const __attribute__((address_space(1))) void*)gb,
                (__attribute__((address_space(3))) void*)(Bs + q * 512), 16, 0, 0);
        }
        __syncthreads();

#pragma unroll
        for (int half = 0; half < 2; ++half) {
            const int kb = half * 4 + (lane >> 4);
            bf16x8 af[4], bfr[4];
#pragma unroll
            for (int m = 0; m < 4; ++m) {
                const int ar = wr * 64 + m * 16 + (lane & 15);
                af[m] = *(const bf16x8*)((const char*)As + ar * 128 + ((kb ^ (ar & 7)) << 4));
            }
#pragma unroll
            for (int n = 0; n < 4; ++n) {
                const int br = wc * 64 + n * 16 + (lane & 15);
                bfr[n] = *(const bf16x8*)((const char*)Bs + br * 128 + ((kb ^ (br & 7)) << 4));
            }
#pragma unroll
            for (int m = 0; m < 4; ++m)
#pragma unroll
                for (int n = 0; n < 4; ++n)
                    acc[m][n] = mfma16(af[m], bfr[n], acc[m][n]);
        }
    }

    const int c_lo = lane & 15;
    const int c_hi = lane >> 4;
    if (MODE == 2) {
#pragma unroll
        for (int m = 0; m < 4; ++m)
#pragma unroll
            for (int n = 0; n < 4; ++n)
#pragma unroll
                for (int r = 0; r < 4; ++r) {
                    const int grow = row0 + wr * 64 + m * 16 + c_hi * 4 + r;
                    const int gcol = col0 + wc * 64 + n * 16 + c_lo;
                    outF[(size_t)grow * 513 + gcol] = acc[m][n][r] + bias[gcol];
                }
    } else { // MODE 4: fused Hutchinson trace
#pragma unroll
        for (int m = 0; m < 4; ++m) {
#pragma unroll
            for (int r = 0; r < 4; ++r) {
                const int grow = row0 + wr * 64 + m * 16 + c_hi * 4 + r;
                float s = 0.f;
#pragma unroll
                for (int n = 0; n < 4; ++n) {
                    const int gcol = col0 + wc * 64 + n * 16 + c_lo;
                    s += acc[m][n][r] * esum[(size_t)grow * 512 + gcol];
                }
                s += __shfl_xor(s, 1);
                s += __shfl_xor(s, 2);
                s += __shfl_xor(s, 4);
                s += __shfl_xor(s, 8);
                if (c_lo == 0)
                    atomicAdd(outF + (size_t)grow * 513 + 512, s * (1.0f / 3.0f));
            }
        }
    }
}

// --------------------------- auxiliary kernels -----------------------------

__global__ void eps_reduce(const float* __restrict__ eps, float* __restrict__ esum, int n)
{
    const float4* e0 = (const float4*)eps;
    const float4* e1 = (const float4*)(eps + (size_t)n);
    const float4* e2 = (const float4*)(eps + 2 * (size_t)n);
    float4* o = (float4*)esum;
    const int n4 = n >> 2;
    const int stride = gridDim.x * blockDim.x;
    for (int i = blockIdx.x * blockDim.x + threadIdx.x; i < n4; i += stride) {
        float4 a = e0[i], b = e1[i], c = e2[i];
        o[i] = make_float4(a.x + b.x + c.x, a.y + b.y + c.y,
                           a.z + b.z + c.z, a.w + b.w + c.w);
    }
}

// zb[b,d] = bf16(aug[b,d]); also zero-init out[:,512] (trace accumulators).
__global__ void z_convert(const float* __restrict__ aug, bf16* __restrict__ zb,
                          float* __restrict__ out)
{
    const int stride = gridDim.x * blockDim.x;
    for (int i = blockIdx.x * blockDim.x + threadIdx.x; i < BATCH * DIM; i += stride) {
        const int b = i >> 9, d = i & 511;
        zb[i] = f2bf(aug[(size_t)b * 513 + d]);
        if (d == 0) out[(size_t)b * 513 + 512] = 0.f;
    }
}

__global__ void conv_bf16(const float* __restrict__ src, bf16* __restrict__ dst, int n)
{
    const int stride = gridDim.x * blockDim.x;
    for (int i = blockIdx.x * blockDim.x + threadIdx.x; i < n; i += stride)
        dst[i] = f2bf(src[i]);
}

__global__ void transpose_bf16(const float* __restrict__ src, bf16* __restrict__ dst,
                               int R, int C)
{
    __shared__ float t[32][33];
    const int bx = blockIdx.x * 32;
    const int by = blockIdx.y * 32;
    const int tx = threadIdx.x & 31;
    const int ty = threadIdx.x >> 5;
#pragma unroll
    for (int j = 0; j < 32; j += 8)
        t[ty + j][tx] = src[(size_t)(by + ty + j) * C + (bx + tx)];
    __syncthreads();
#pragma unroll
    for (int j = 0; j < 32; j += 8)
        dst[(size_t)(bx + ty + j) * R + (by + tx)] = f2bf(t[tx][ty + j]);
}

__global__ void colsum(const float* __restrict__ W3, float* __restrict__ u3)
{
    const int j = blockIdx.x * blockDim.x + threadIdx.x;
    if (j >= HIDDEN) return;
    float s = 0.f;
    for (int i = 0; i < DIM; ++i) s += W3[(size_t)i * HIDDEN + j];
    u3[j] = s;
}

// ---------------------------------------------------------------------------
extern "C" void kernel_launch(void* const* d_in, const int* in_sizes, int n_in,
                              void* d_out, int out_size, void* d_ws, size_t ws_size,
                              hipStream_t stream)
{
    const float* aug = (const float*)d_in[1];
    const float* eps = (const float*)d_in[2];
    const float* W1  = (const float*)d_in[3];
    const float* b1  = (const float*)d_in[4];
    const float* W2  = (const float*)d_in[5];
    const float* b2  = (const float*)d_in[6];
    const float* W3  = (const float*)d_in[7];
    const float* b3  = (const float*)d_in[8];
    float* out = (float*)d_out;

    char* ws = (char*)d_ws;
    size_t off = 0;
    auto alloc = [&](size_t bytes) {
        char* p = ws + off;
        off += (bytes + 255) & ~(size_t)255;
        return p;
    };
    bf16*  zb   = (bf16*)alloc((size_t)BATCH * DIM * 2);
    bf16*  h1   = (bf16*)alloc((size_t)BATCH * HIDDEN * 2);
    bf16*  h2   = (bf16*)alloc((size_t)BATCH * HIDDEN * 2);  // reused as d1 after G3
    bf16*  d2   = (bf16*)alloc((size_t)BATCH * HIDDEN * 2);
    float* esum = (float*)alloc((size_t)BATCH * DIM * 4);
    bf16*  W1b  = (bf16*)alloc((size_t)HIDDEN * DIM * 2);
    bf16*  W2b  = (bf16*)alloc((size_t)HIDDEN * HIDDEN * 2);
    bf16*  W3b  = (bf16*)alloc((size_t)DIM * HIDDEN * 2);
    bf16*  W2t  = (bf16*)alloc((size_t)HIDDEN * HIDDEN * 2);
    bf16*  W1t  = (bf16*)alloc((size_t)DIM * HIDDEN * 2);
    float* u3   = (float*)alloc((size_t)HIDDEN * 4);
    bf16*  d1   = h2;

    // --- preprocessing ---
    eps_reduce<<<2048, 256, 0, stream>>>(eps, esum, BATCH * DIM);
    z_convert<<<2048, 256, 0, stream>>>(aug, zb, out);
    conv_bf16<<<1024, 256, 0, stream>>>(W1, W1b, HIDDEN * DIM);
    conv_bf16<<<2048, 256, 0, stream>>>(W2, W2b, HIDDEN * HIDDEN);
    conv_bf16<<<1024, 256, 0, stream>>>(W3, W3b, DIM * HIDDEN);
    transpose_bf16<<<dim3(HIDDEN / 32, HIDDEN / 32), 256, 0, stream>>>(W2, W2t, HIDDEN, HIDDEN);
    transpose_bf16<<<dim3(DIM / 32, HIDDEN / 32), 256, 0, stream>>>(W1, W1t, HIDDEN, DIM);
    colsum<<<HIDDEN / 256, 256, 0, stream>>>(W3, u3);

    // --- forward ---
    dim3 g8(BATCH / 256, HIDDEN / 256);     // 64 x 8 = 512 blocks
    dim3 gSml(BATCH / 128, DIM / 128);      // 128 x 4 = 512 blocks
    // h1 = tanh(z @ W1^T + b1)
    gemm8<0><<<g8, 512, 0, stream>>>(zb, W1b, BATCH, HIDDEN, DIM, b1,
                                     h1, nullptr, nullptr, nullptr);
    // h2 = tanh(h1 @ W2^T + b2);  d2 = u3 * (1 - h2^2)
    gemm8<1><<<g8, 512, 0, stream>>>(h1, W2b, BATCH, HIDDEN, HIDDEN, b2,
                                     h2, d2, u3, nullptr);
    // dz_dt = h2 @ W3^T + b3  -> out[:, 0:512] (stride 513)
    gemm_bt<2><<<gSml, 256, 0, stream>>>(h2, W3b, BATCH, DIM, HIDDEN, b3, out, nullptr);
    // --- backward ---
    // d1 = (d2 @ W2) * (1 - h1^2)
    gemm8<3><<<g8, 512, 0, stream>>>(d2, W2t, BATCH, HIDDEN, HIDDEN, nullptr,
                                     d1, nullptr, nullptr, h1);
    // g = d1 @ W1 fused with trace: out[:,512] += dot(esum_row, g_row)/3
    gemm_bt<4><<<gSml, 256, 0, stream>>>(d1, W1t, BATCH, DIM, HIDDEN, nullptr, out, esum);
}

// Round 6
// 659.946 us; speedup vs baseline: 1.0115x; 1.0115x over previous
//
#include <hip/hip_runtime.h>
#include <hip/hip_bf16.h>
#include <stdint.h>

#define DIM 512
#define HIDDEN 2048
#define BATCH 16384

using bf16 = __hip_bfloat16;
typedef float f32x4 __attribute__((ext_vector_type(4)));
typedef short bf16x8 __attribute__((ext_vector_type(8)));

__device__ __forceinline__ float bf2f(bf16 x) { return __bfloat162float(x); }
__device__ __forceinline__ bf16 f2bf(float x) { return __float2bfloat16(x); }

// fast tanh: 1 - 2/(e^{2x}+1).
__device__ __forceinline__ float fast_tanh(float x) {
    float e = __expf(2.0f * x);
    return 1.0f - 2.0f * __builtin_amdgcn_rcpf(e + 1.0f);
}

__device__ __forceinline__ f32x4 mfma16(bf16x8 a, bf16x8 b, f32x4 c) {
    return __builtin_amdgcn_mfma_f32_16x16x32_bf16(a, b, c, 0, 0, 0);
}

#define SBAR()  __builtin_amdgcn_s_barrier()
#define FENCE() __builtin_amdgcn_sched_barrier(0)
// pre-MFMA drain: fence REQUIRED (rule #18: MFMA hoists past asm lgkmcnt)
#define LGK0F() do { asm volatile("s_waitcnt lgkmcnt(0)" ::: "memory"); \
                     __builtin_amdgcn_sched_barrier(0); } while (0)
#define VMC4()  asm volatile("s_waitcnt vmcnt(4)" ::: "memory")

// stage one K-half of a 256-row tile: 256 rows x 32 cols bf16 = 16KB.
// LDS linear [row][slot(16B)] (4 slots/row). Swizzle f(row) = (row>>1)&3
// applied on the GLOBAL source (rule #21); ds_read side XORs the same f.
// Verified r4: 0 bank conflicts.
__device__ __forceinline__ void stage_half(const bf16* __restrict__ G, int grow0,
                                           int Kdim, int kbase, bf16* lds,
                                           int elem_base, int wave, int srow4, int gs8)
{
#pragma unroll
    for (int i = 0; i < 2; ++i) {
        const int q = wave * 2 + i;
        const bf16* ga = G + (size_t)(grow0 + q * 16 + srow4) * Kdim + kbase + gs8;
        __builtin_amdgcn_global_load_lds(
            (const __attribute__((address_space(1))) void*)ga,
            (__attribute__((address_space(3))) void*)(lds + elem_base + q * 512), 16, 0, 0);
    }
}

// ---------------------------------------------------------------------------
// 8-phase 256x256 GEMM: C[M,N] = A[M,K] @ Bt[N,K]^T (both bf16 row-major).
// 8 waves (2M x 4N), per-wave 128x64, BK=64, LDS 128KB dbuf.
// Round-4 phase structure (8/4/8/4 ds_reads, stage 1 half/phase, vmcnt(4) at
// ph2/ph4, setprio around MFMA) but MINIMAL scheduler fencing: bare s_barrier
// at phase boundaries; sched_barrier(0) only after pre-MFMA lgkmcnt(0) (rule
// #18) and after the two vmcnt-barriers (buffer-flip boundaries). This lets
// the compiler interleave phase p+1's ds_reads with phase p's MFMA cluster
// (m141: full fencing was the ~40%-util cap). Memory ordering across the
// waits is preserved by the asm "memory" clobbers.
// ---------------------------------------------------------------------------
template <int MODE>
__global__ __launch_bounds__(512, 2)
void gemm8(const bf16* __restrict__ A, const bf16* __restrict__ Bt,
           int M, int N, int K,
           const float* __restrict__ bias,
           bf16* __restrict__ out1, bf16* __restrict__ out2,
           const float* __restrict__ u3, const bf16* __restrict__ h1s)
{
    __shared__ bf16 lds[65536];   // 128 KiB
    const int tid  = threadIdx.x;
    const int lane = tid & 63;
    const int wave = tid >> 6;

    // XCD-aware, M-major within each XCD chunk (A-panel L2 locality)
    const int nwg = gridDim.x * gridDim.y;
    const int bid = blockIdx.y * gridDim.x + blockIdx.x;
    const int cpx = nwg >> 3;
    const int sw  = (bid & 7) * cpx + (bid >> 3);
    const int nbn = N >> 8;
    const int bm  = sw / nbn;
    const int bn  = sw % nbn;
    const int row0 = bm << 8;
    const int col0 = bn << 8;

    const int wr = wave >> 2;       // 0..1 (M)
    const int wc = wave & 3;        // 0..3 (N)
    const int l15 = lane & 15;

    // ds_read per-lane offsets: row stride 64B, stored slot = (lane>>4) ^ f(row)
    const int slotl    = (((lane >> 4) ^ ((l15 >> 1) & 3)) << 4);
    const int laneoffA = (wr * 128 + l15) * 64 + slotl;
    const int laneoffB = (wc * 64  + l15) * 64 + slotl;
    // staging constants
    const int srow4 = lane >> 2;
    const int gs8   = (((lane & 3) ^ ((lane >> 3) & 3)) << 3);

    const char* ldsc = (const char*)lds;
    f32x4 acc[8][4] = {};
    bf16x8 af[4], bfv[4];

    // prologue: tile 0 -> dbuf 0
    stage_half(A,  row0, K, 0,  lds, 0,     wave, srow4, gs8);   // A k-half0
    stage_half(Bt, col0, K, 0,  lds, 16384, wave, srow4, gs8);   // B k-half0
    stage_half(A,  row0, K, 32, lds, 8192,  wave, srow4, gs8);   // A k-half1
    stage_half(Bt, col0, K, 32, lds, 24576, wave, srow4, gs8);   // B k-half1
    VMC4(); SBAR(); FENCE();

    const int KT = K >> 6;
    for (int t = 0; t < KT; ++t) {
        const int cur = t & 1;
        const int cb  = cur << 16;            // byte base of current dbuf
        const int ce  = (cur ^ 1) << 15;      // elem base of next dbuf
        const int knt = ((t + 1 < KT) ? t + 1 : 0) << 6;

        // ---- phase 1: ks0, m0-3 x n0-3 (8 reads) ----
#pragma unroll
        for (int j = 0; j < 4; ++j)
            af[j] = *(const bf16x8*)(ldsc + cb + j * 1024 + laneoffA);
#pragma unroll
        for (int j = 0; j < 4; ++j)
            bfv[j] = *(const bf16x8*)(ldsc + cb + 32768 + j * 1024 + laneoffB);
        stage_half(A, row0, K, knt, lds, ce, wave, srow4, gs8);          // A_k0'
        SBAR(); LGK0F();
        __builtin_amdgcn_s_setprio(1);
#pragma unroll
        for (int m = 0; m < 4; ++m)
#pragma unroll
            for (int n = 0; n < 4; ++n)
                acc[m][n] = mfma16(af[m], bfv[n], acc[m][n]);
        __builtin_amdgcn_s_setprio(0);

        // ---- phase 2: ks0, m4-7 x n0-3 (4 reads, reuse bfv) ----
#pragma unroll
        for (int j = 0; j < 4; ++j)
            af[j] = *(const bf16x8*)(ldsc + cb + (4 + j) * 1024 + laneoffA);
        stage_half(Bt, col0, K, knt, lds, ce + 16384, wave, srow4, gs8); // B_k0'
        SBAR(); LGK0F();
        __builtin_amdgcn_s_setprio(1);
#pragma unroll
        for (int m = 0; m < 4; ++m)
#pragma unroll
            for (int n = 0; n < 4; ++n)
                acc[4 + m][n] = mfma16(af[m], bfv[n], acc[4 + m][n]);
        __builtin_amdgcn_s_setprio(0);
        VMC4();          // A_k1(t), B_k1(t) landed (needed by ph3)
        SBAR(); FENCE();

        // ---- phase 3: ks1, m0-3 x n0-3 (8 reads) ----
#pragma unroll
        for (int j = 0; j < 4; ++j)
            af[j] = *(const bf16x8*)(ldsc + cb + 16384 + j * 1024 + laneoffA);
#pragma unroll
        for (int j = 0; j < 4; ++j)
            bfv[j] = *(const bf16x8*)(ldsc + cb + 49152 + j * 1024 + laneoffB);
        stage_half(A, row0, K, knt + 32, lds, ce + 8192, wave, srow4, gs8);  // A_k1'
        SBAR(); LGK0F();
        __builtin_amdgcn_s_setprio(1);
#pragma unroll
        for (int m = 0; m < 4; ++m)
#pragma unroll
            for (int n = 0; n < 4; ++n)
                acc[m][n] = mfma16(af[m], bfv[n], acc[m][n]);
        __builtin_amdgcn_s_setprio(0);

        // ---- phase 4: ks1, m4-7 x n0-3 (4 reads) ----
#pragma unroll
        for (int j = 0; j < 4; ++j)
            af[j] = *(const bf16x8*)(ldsc + cb + 16384 + (4 + j) * 1024 + laneoffA);
        stage_half(Bt, col0, K, knt + 32, lds, ce + 24576, wave, srow4, gs8); // B_k1'
        SBAR(); LGK0F();
        __builtin_amdgcn_s_setprio(1);
#pragma unroll
        for (int m = 0; m < 4; ++m)
#pragma unroll
            for (int n = 0; n < 4; ++n)
                acc[4 + m][n] = mfma16(af[m], bfv[n], acc[4 + m][n]);
        __builtin_amdgcn_s_setprio(0);
        VMC4();          // A_k0(t+1), B_k0(t+1) landed (needed by next ph1)
        SBAR(); FENCE(); // buffer flip boundary
    }

    // Epilogue. C/D: col = lane&15, row = (lane>>4)*4 + reg.
    const int c4 = (lane >> 4) << 2;
#pragma unroll
    for (int m = 0; m < 8; ++m) {
        const int growb = row0 + wr * 128 + m * 16 + c4;
#pragma unroll
        for (int n = 0; n < 4; ++n) {
            const int gcol = col0 + wc * 64 + n * 16 + l15;
            const float bz = (MODE == 3) ? 0.0f : bias[gcol];
            const float uu = (MODE == 1) ? u3[gcol] : 0.0f;
#pragma unroll
            for (int r = 0; r < 4; ++r) {
                const size_t idx = (size_t)(growb + r) * N + gcol;
                const float cv = acc[m][n][r];
                if (MODE == 0) {
                    out1[idx] = f2bf(fast_tanh(cv + bz));
                } else if (MODE == 1) {
                    float v = fast_tanh(cv + bz);
                    out1[idx] = f2bf(v);
                    out2[idx] = f2bf(uu * (1.0f - v * v));
                } else { // MODE 3
                    float h = bf2f(h1s[idx]);
                    out1[idx] = f2bf(cv * (1.0f - h * h));
                }
            }
        }
    }
}

// ---------------------------------------------------------------------------
// 128x128 m97-structure GEMM for the N=512 outputs.
// MODE 2: outF[row*513 + col] = acc + bias[col]            (dz_dt)
// MODE 4: trace fused — atomicAdd(out[row*513+512], dot(esum_row, g_row)/3)
// ---------------------------------------------------------------------------
template <int MODE>
__global__ __launch_bounds__(256)
void gemm_bt(const bf16* __restrict__ A, const bf16* __restrict__ Bt,
             int M, int N, int K,
             const float* __restrict__ bias,
             float* __restrict__ outF,
             const float* __restrict__ esum)
{
    __shared__ __align__(128) bf16 As[128 * 64];
    __shared__ __align__(128) bf16 Bs[128 * 64];

    const int tid  = threadIdx.x;
    const int lane = tid & 63;
    const int wave = tid >> 6;

    const int nwg = gridDim.x * gridDim.y;
    const int bid = blockIdx.y * gridDim.x + blockIdx.x;
    const int cpx = nwg >> 3;
    const int sw  = (bid & 7) * cpx + (bid >> 3);
    const int nbn = N >> 7;
    const int bm  = sw / nbn;
    const int bn  = sw % nbn;
    const int row0 = bm << 7;
    const int col0 = bn << 7;

    const int wr = wave >> 1;
    const int wc = wave & 1;

    f32x4 acc[4][4] = {};

    const int srow  = lane >> 3;
    const int sslot = lane & 7;

    const int KT = K >> 6;
    for (int kt = 0; kt < KT; ++kt) {
        const int k0 = kt << 6;
        __syncthreads();
#pragma unroll
        for (int i = 0; i < 4; ++i) {
            const int q   = wave * 4 + i;
            const int row = q * 8 + srow;
            const int gs  = sslot ^ (row & 7);
            const bf16* ga = A  + (size_t)(row0 + row) * K + (k0 + gs * 8);
            const bf16* gb = Bt + (size_t)(col0 + row) * K + (k0 + gs * 8);
            __builtin_amdgcn_global_load_lds(
                (const __attribute__((address_space(1))) void*)ga,
                (__attribute__((address_space(3))) void*)(As + q * 512), 16, 0, 0);
            __builtin_amdgcn_global_load_lds(
                (const __attribute__((address_space(1))) void*)gb,
                (__attribute__((address_space(3))) void*)(Bs + q * 512), 16, 0, 0);
        }
        __syncthreads();

#pragma unroll
        for (int half = 0; half < 2; ++half) {
            const int kb = half * 4 + (lane >> 4);
            bf16x8 af[4], bfr[4];
#pragma unroll
            for (int m = 0; m < 4; ++m) {
                const int ar = wr * 64 + m * 16 + (lane & 15);
                af[m] = *(const bf16x8*)((const char*)As + ar * 128 + ((kb ^ (ar & 7)) << 4));
            }
#pragma unroll
            for (int n = 0; n < 4; ++n) {
                const int br = wc * 64 + n * 16 + (lane & 15);
                bfr[n] = *(const bf16x8*)((const char*)Bs + br * 128 + ((kb ^ (br & 7)) << 4));
            }
#pragma unroll
            for (int m = 0; m < 4; ++m)
#pragma unroll
                for (int n = 0; n < 4; ++n)
                    acc[m][n] = mfma16(af[m], bfr[n], acc[m][n]);
        }
    }

    const int c_lo = lane & 15;
    const int c_hi = lane >> 4;
    if (MODE == 2) {
#pragma unroll
        for (int m = 0; m < 4; ++m)
#pragma unroll
            for (int n = 0; n < 4; ++n)
#pragma unroll
                for (int r = 0; r < 4; ++r) {
                    const int grow = row0 + wr * 64 + m * 16 + c_hi * 4 + r;
                    const int gcol = col0 + wc * 64 + n * 16 + c_lo;
                    outF[(size_t)grow * 513 + gcol] = acc[m][n][r] + bias[gcol];
                }
    } else { // MODE 4: fused Hutchinson trace
#pragma unroll
        for (int m = 0; m < 4; ++m) {
#pragma unroll
            for (int r = 0; r < 4; ++r) {
                const int grow = row0 + wr * 64 + m * 16 + c_hi * 4 + r;
                float s = 0.f;
#pragma unroll
                for (int n = 0; n < 4; ++n) {
                    const int gcol = col0 + wc * 64 + n * 16 + c_lo;
                    s += acc[m][n][r] * esum[(size_t)grow * 512 + gcol];
                }
                s += __shfl_xor(s, 1);
                s += __shfl_xor(s, 2);
                s += __shfl_xor(s, 4);
                s += __shfl_xor(s, 8);
                if (c_lo == 0)
                    atomicAdd(outF + (size_t)grow * 513 + 512, s * (1.0f / 3.0f));
            }
        }
    }
}

// --------------------------- auxiliary kernels -----------------------------

__global__ void eps_reduce(const float* __restrict__ eps, float* __restrict__ esum, int n)
{
    const float4* e0 = (const float4*)eps;
    const float4* e1 = (const float4*)(eps + (size_t)n);
    const float4* e2 = (const float4*)(eps + 2 * (size_t)n);
    float4* o = (float4*)esum;
    const int n4 = n >> 2;
    const int stride = gridDim.x * blockDim.x;
    for (int i = blockIdx.x * blockDim.x + threadIdx.x; i < n4; i += stride) {
        float4 a = e0[i], b = e1[i], c = e2[i];
        o[i] = make_float4(a.x + b.x + c.x, a.y + b.y + c.y,
                           a.z + b.z + c.z, a.w + b.w + c.w);
    }
}

// zb[b,d] = bf16(aug[b,d]); also zero-init out[:,512] (trace accumulators).
__global__ void z_convert(const float* __restrict__ aug, bf16* __restrict__ zb,
                          float* __restrict__ out)
{
    const int stride = gridDim.x * blockDim.x;
    for (int i = blockIdx.x * blockDim.x + threadIdx.x; i < BATCH * DIM; i += stride) {
        const int b = i >> 9, d = i & 511;
        zb[i] = f2bf(aug[(size_t)b * 513 + d]);
        if (d == 0) out[(size_t)b * 513 + 512] = 0.f;
    }
}

__global__ void conv_bf16(const float* __restrict__ src, bf16* __restrict__ dst, int n)
{
    const int stride = gridDim.x * blockDim.x;
    for (int i = blockIdx.x * blockDim.x + threadIdx.x; i < n; i += stride)
        dst[i] = f2bf(src[i]);
}

__global__ void transpose_bf16(const float* __restrict__ src, bf16* __restrict__ dst,
                               int R, int C)
{
    __shared__ float t[32][33];
    const int bx = blockIdx.x * 32;
    const int by = blockIdx.y * 32;
    const int tx = threadIdx.x & 31;
    const int ty = threadIdx.x >> 5;
#pragma unroll
    for (int j = 0; j < 32; j += 8)
        t[ty + j][tx] = src[(size_t)(by + ty + j) * C + (bx + tx)];
    __syncthreads();
#pragma unroll
    for (int j = 0; j < 32; j += 8)
        dst[(size_t)(bx + ty + j) * R + (by + tx)] = f2bf(t[tx][ty + j]);
}

__global__ void colsum(const float* __restrict__ W3, float* __restrict__ u3)
{
    const int j = blockIdx.x * blockDim.x + threadIdx.x;
    if (j >= HIDDEN) return;
    float s = 0.f;
    for (int i = 0; i < DIM; ++i) s += W3[(size_t)i * HIDDEN + j];
    u3[j] = s;
}

// ---------------------------------------------------------------------------
extern "C" void kernel_launch(void* const* d_in, const int* in_sizes, int n_in,
                              void* d_out, int out_size, void* d_ws, size_t ws_size,
                              hipStream_t stream)
{
    const float* aug = (const float*)d_in[1];
    const float* eps = (const float*)d_in[2];
    const float* W1  = (const float*)d_in[3];
    const float* b1  = (const float*)d_in[4];
    const float* W2  = (const float*)d_in[5];
    const float* b2  = (const float*)d_in[6];
    const float* W3  = (const float*)d_in[7];
    const float* b3  = (const float*)d_in[8];
    float* out = (float*)d_out;

    char* ws = (char*)d_ws;
    size_t off = 0;
    auto alloc = [&](size_t bytes) {
        char* p = ws + off;
        off += (bytes + 255) & ~(size_t)255;
        return p;
    };
    bf16*  zb   = (bf16*)alloc((size_t)BATCH * DIM * 2);
    bf16*  h1   = (bf16*)alloc((size_t)BATCH * HIDDEN * 2);
    bf16*  h2   = (bf16*)alloc((size_t)BATCH * HIDDEN * 2);  // reused as d1 after G3
    bf16*  d2   = (bf16*)alloc((size_t)BATCH * HIDDEN * 2);
    float* esum = (float*)alloc((size_t)BATCH * DIM * 4);
    bf16*  W1b  = (bf16*)alloc((size_t)HIDDEN * DIM * 2);
    bf16*  W2b  = (bf16*)alloc((size_t)HIDDEN * HIDDEN * 2);
    bf16*  W3b  = (bf16*)alloc((size_t)DIM * HIDDEN * 2);
    bf16*  W2t  = (bf16*)alloc((size_t)HIDDEN * HIDDEN * 2);
    bf16*  W1t  = (bf16*)alloc((size_t)DIM * HIDDEN * 2);
    float* u3   = (float*)alloc((size_t)HIDDEN * 4);
    bf16*  d1   = h2;

    // --- preprocessing ---
    eps_reduce<<<2048, 256, 0, stream>>>(eps, esum, BATCH * DIM);
    z_convert<<<2048, 256, 0, stream>>>(aug, zb, out);
    conv_bf16<<<1024, 256, 0, stream>>>(W1, W1b, HIDDEN * DIM);
    conv_bf16<<<2048, 256, 0, stream>>>(W2, W2b, HIDDEN * HIDDEN);
    conv_bf16<<<1024, 256, 0, stream>>>(W3, W3b, DIM * HIDDEN);
    transpose_bf16<<<dim3(HIDDEN / 32, HIDDEN / 32), 256, 0, stream>>>(W2, W2t, HIDDEN, HIDDEN);
    transpose_bf16<<<dim3(DIM / 32, HIDDEN / 32), 256, 0, stream>>>(W1, W1t, HIDDEN, DIM);
    colsum<<<HIDDEN / 256, 256, 0, stream>>>(W3, u3);

    // --- forward ---
    dim3 g8(BATCH / 256, HIDDEN / 256);     // 64 x 8 = 512 blocks
    dim3 gSml(BATCH / 128, DIM / 128);      // 128 x 4 = 512 blocks
    // h1 = tanh(z @ W1^T + b1)
    gemm8<0><<<g8, 512, 0, stream>>>(zb, W1b, BATCH, HIDDEN, DIM, b1,
                                     h1, nullptr, nullptr, nullptr);
    // h2 = tanh(h1 @ W2^T + b2);  d2 = u3 * (1 - h2^2)
    gemm8<1><<<g8, 512, 0, stream>>>(h1, W2b, BATCH, HIDDEN, HIDDEN, b2,
                                     h2, d2, u3, nullptr);
    // dz_dt = h2 @ W3^T + b3  -> out[:, 0:512] (stride 513)
    gemm_bt<2><<<gSml, 256, 0, stream>>>(h2, W3b, BATCH, DIM, HIDDEN, b3, out, nullptr);
    // --- backward ---
    // d1 = (d2 @ W2) * (1 - h1^2)
    gemm8<3><<<g8, 512, 0, stream>>>(d2, W2t, BATCH, HIDDEN, HIDDEN, nullptr,
                                     d1, nullptr, nullptr, h1);
    // g = d1 @ W1 fused with trace: out[:,512] += dot(esum_row, g_row)/3
    gemm_bt<4><<<gSml, 256, 0, stream>>>(d1, W1t, BATCH, DIM, HIDDEN, nullptr, out, esum);
}